// Round 8
// baseline (4129.346 us; speedup 1.0000x reference)
//
#include <hip/hip_runtime.h>
#include <hip/hip_bf16.h>

#define B_   64
#define T_   2048
#define H_   128
#define G_   384      // 3*H
#define D0_  18
#define WIN  4
#define RING 5
#define NW   (T_ / WIN)   // 512
#define HSTR 136          // h ring row stride in shorts

typedef __hip_bfloat16 bf16;
typedef __attribute__((ext_vector_type(4))) float f32x4;
typedef __attribute__((ext_vector_type(8))) short s16x8;

#define LOG2E 1.4426950408889634f
__device__ __forceinline__ float sigf(float x) {
    return __builtin_amdgcn_rcpf(1.0f + __builtin_amdgcn_exp2f(-LOG2E * x));
}
__device__ __forceinline__ float tanhf_(float x) {
    return 1.0f - 2.0f * __builtin_amdgcn_rcpf(1.0f + __builtin_amdgcn_exp2f((2.0f * LOG2E) * x));
}
__device__ __forceinline__ float us2f(unsigned short u) {
    return __uint_as_float(((unsigned)u) << 16);
}
__device__ __forceinline__ short f2bs(float v) {
    bf16 b = __float2bfloat16(v);
    return *reinterpret_cast<short*>(&b);
}

// ---------------------------------------------------------------------------
// Layer 0 MFMA scan. 8 WGs: dir = bx>>2, batch-group bg = bx&3 (16 batches).
// 512 thr = 8 waves; wave wv owns gate columns j in [16wv,16wv+16).
// Per step: gates = mfma(h_Afrag, Whh_Bfrag) + fused x-projection K-tile.
// h in RING=5 LDS buffers (1 barrier/step); h history flushed per window.
// ---------------------------------------------------------------------------
__global__ __launch_bounds__(512, 2) void gru_l0_mfma(
    const float* __restrict__ x,
    const float* __restrict__ wih_f, const float* __restrict__ whh_f,
    const float* __restrict__ bih_f, const float* __restrict__ bhh_f,
    const float* __restrict__ wih_r, const float* __restrict__ whh_r,
    const float* __restrict__ bih_r, const float* __restrict__ bhh_r,
    bf16* __restrict__ l0h)
{
    const int bx   = blockIdx.x;
    const int dir  = bx >> 2;
    const int bg   = bx & 3;
    const int b0   = bg * 16;
    const int tid  = threadIdx.x;
    const int lane = tid & 63;
    const int wv   = tid >> 6;
    const int col  = lane & 15;
    const int quad = lane >> 4;
    const int jcol = wv * 16 + col;

    const float* Wih = dir ? wih_r : wih_f;
    const float* Whh = dir ? whh_r : whh_f;
    const float* Bih = dir ? bih_r : bih_f;
    const float* Bhh = dir ? bhh_r : bhh_f;

    __shared__ __align__(16) bf16 hring[RING][16 * HSTR];
    __shared__ __align__(16) bf16 xbuf[WIN][16][40];

    // B-frags: W_hh (3 gates x 4 K-tiles) + W_ih x-tile (3 gates, K=32 zero-pad)
    s16x8 bfr[3][4], bxf[3];
    #pragma unroll
    for (int g = 0; g < 3; ++g) {
        const float* wrow = Whh + (size_t)(g * H_ + jcol) * H_;
        #pragma unroll
        for (int kt = 0; kt < 4; ++kt) {
            const float* p = wrow + kt * 32 + quad * 8;
            s16x8 f;
            #pragma unroll
            for (int i = 0; i < 8; ++i) f[i] = f2bs(p[i]);
            bfr[g][kt] = f;
        }
        const float* xrow = Wih + (size_t)(g * H_ + jcol) * D0_;
        s16x8 fx;
        #pragma unroll
        for (int i = 0; i < 8; ++i) {
            const int k = quad * 8 + i;
            fx[i] = (k < D0_) ? f2bs(xrow[k]) : (short)0;
        }
        bxf[g] = fx;
    }
    const float cr  = Bih[jcol]        + Bhh[jcol];
    const float cz  = Bih[H_ + jcol]   + Bhh[H_ + jcol];
    const float bnx = Bih[2*H_ + jcol];
    const float bnh = Bhh[2*H_ + jcol];

    // zero h_{-1}; zero xbuf pad cols 24..39
    for (int i = tid; i < 16 * HSTR; i += 512) hring[0][i] = __float2bfloat16(0.0f);
    for (int i = tid; i < WIN * 16 * 16; i += 512) {
        const int si = i >> 8, rem = i & 255;
        xbuf[si][rem >> 4][24 + (rem & 15)] = __float2bfloat16(0.0f);
    }
    // stage x window 0
    for (int i = tid; i < WIN * 16 * 24; i += 512) {
        const int si = i / 384, rem = i % 384, m = rem / 24, c = rem % 24;
        const int t = dir ? (T_ - 1 - si) : si;
        const float v = (c < D0_) ? x[((size_t)(b0 + m) * T_ + t) * D0_ + c] : 0.0f;
        xbuf[si][m][c] = __float2bfloat16(v);
    }
    __syncthreads();

    float hprev[4] = {0.f, 0.f, 0.f, 0.f};

    for (int w = 0; w < NW; ++w) {
        #pragma unroll
        for (int si = 0; si < WIN; ++si) {
            const int s  = w * WIN + si;
            const int rb = s % RING;
            const int wb = (s + 1) % RING;

            s16x8 afr[4];
            #pragma unroll
            for (int kt = 0; kt < 4; ++kt)
                afr[kt] = *(const s16x8*)&hring[rb][col * HSTR + kt * 32 + quad * 8];
            const s16x8 axf = *(const s16x8*)&xbuf[si][col][quad * 8];

            f32x4 aR = (f32x4){0.f,0.f,0.f,0.f};
            f32x4 aZ = aR, aN = aR, aX = aR;
            #pragma unroll
            for (int kt = 0; kt < 4; ++kt) {
                aR = __builtin_amdgcn_mfma_f32_16x16x32_bf16(afr[kt], bfr[0][kt], aR, 0, 0, 0);
                aZ = __builtin_amdgcn_mfma_f32_16x16x32_bf16(afr[kt], bfr[1][kt], aZ, 0, 0, 0);
                aN = __builtin_amdgcn_mfma_f32_16x16x32_bf16(afr[kt], bfr[2][kt], aN, 0, 0, 0);
            }
            aR = __builtin_amdgcn_mfma_f32_16x16x32_bf16(axf, bxf[0], aR, 0, 0, 0);
            aZ = __builtin_amdgcn_mfma_f32_16x16x32_bf16(axf, bxf[1], aZ, 0, 0, 0);
            aX = __builtin_amdgcn_mfma_f32_16x16x32_bf16(axf, bxf[2], aX, 0, 0, 0);

            #pragma unroll
            for (int r = 0; r < 4; ++r) {
                const float rg = sigf(aR[r] + cr);
                const float zg = sigf(aZ[r] + cz);
                const float ng = tanhf_(aX[r] + bnx + rg * (aN[r] + bnh));
                const float hn = ng + zg * (hprev[r] - ng);
                hprev[r] = hn;
                hring[wb][(quad * 4 + r) * HSTR + jcol] = __float2bfloat16(hn);
            }
            __syncthreads();
        }

        // flush h history (WIN x 16 x 128 bf16) + stage next x window
        #pragma unroll
        for (int k = 0; k < 2; ++k) {
            const int c  = tid + k * 512;            // 1024 chunks
            const int dt = c >> 8, m = (c >> 4) & 15, j8 = c & 15;
            const int s  = w * WIN + dt;
            const int t  = dir ? (T_ - 1 - s) : s;
            const uint4 v = *(const uint4*)&hring[(s + 1) % RING][m * HSTR + j8 * 8];
            *(uint4*)(l0h + ((size_t)(b0 + m) * T_ + t) * 256 + dir * H_ + j8 * 8) = v;
        }
        if (w + 1 < NW) {
            for (int i = tid; i < WIN * 16 * 24; i += 512) {
                const int si = i / 384, rem = i % 384, m = rem / 24, c = rem % 24;
                const int s  = (w + 1) * WIN + si;
                const int t  = dir ? (T_ - 1 - s) : s;
                const float v = (c < D0_) ? x[((size_t)(b0 + m) * T_ + t) * D0_ + c] : 0.0f;
                xbuf[si][m][c] = __float2bfloat16(v);
            }
        }
        __syncthreads();
    }
}

// ---------------------------------------------------------------------------
// xg GEMM: C(131072x384) = l0h(131072x256,bf16) . W^T(384x256 fp32) + bias.
// Output layout scan-friendly: xg[(bg*2048+t)*384 + g][16 lb] bf16.
// ---------------------------------------------------------------------------
__global__ __launch_bounds__(256, 2) void xg_gemm_mfma(
    const bf16* __restrict__ A,
    const float* __restrict__ W, const float* __restrict__ bias,
    bf16* __restrict__ xg)
{
    __shared__ short As[128 * 40];
    __shared__ short Ws[128 * 40];
    __shared__ float Bias_s[128];

    const int tid  = threadIdx.x;
    const int lane = tid & 63;
    const int wv   = tid >> 6;
    const int m0   = blockIdx.x * 128;
    const int n0   = blockIdx.y * 128;

    if (tid < 128) Bias_s[tid] = bias[n0 + tid];

    f32x4 acc[2][8];
    #pragma unroll
    for (int mt = 0; mt < 2; ++mt)
        #pragma unroll
        for (int nt = 0; nt < 8; ++nt) acc[mt][nt] = (f32x4){0.f, 0.f, 0.f, 0.f};

    for (int k0 = 0; k0 < 256; k0 += 32) {
        #pragma unroll
        for (int i = 0; i < 2; ++i) {
            const int c = tid + i * 256;
            const int row = c >> 2, quad = c & 3;
            *(uint4*)&As[row * 40 + quad * 8] =
                *(const uint4*)(A + (size_t)(m0 + row) * 256 + k0 + quad * 8);
        }
        #pragma unroll
        for (int i = 0; i < 4; ++i) {
            const int c = tid + i * 256;
            const int row = c >> 3, q = c & 7;
            const float4 v = *(const float4*)(W + (size_t)(n0 + row) * 256 + k0 + q * 4);
            ushort4 u;
            u.x = (unsigned short)f2bs(v.x); u.y = (unsigned short)f2bs(v.y);
            u.z = (unsigned short)f2bs(v.z); u.w = (unsigned short)f2bs(v.w);
            *(ushort4*)&Ws[row * 40 + q * 4] = u;
        }
        __syncthreads();

        s16x8 afr[2], bfr[8];
        #pragma unroll
        for (int mt = 0; mt < 2; ++mt)
            afr[mt] = *(const s16x8*)&As[(wv * 32 + mt * 16 + (lane & 15)) * 40 + (lane >> 4) * 8];
        #pragma unroll
        for (int nt = 0; nt < 8; ++nt)
            bfr[nt] = *(const s16x8*)&Ws[(nt * 16 + (lane & 15)) * 40 + (lane >> 4) * 8];

        #pragma unroll
        for (int mt = 0; mt < 2; ++mt)
            #pragma unroll
            for (int nt = 0; nt < 8; ++nt)
                acc[mt][nt] = __builtin_amdgcn_mfma_f32_16x16x32_bf16(
                    afr[mt], bfr[nt], acc[mt][nt], 0, 0, 0);
        __syncthreads();
    }

    // epilogue: write into [bg][t][g][16] layout
    #pragma unroll
    for (int mt = 0; mt < 2; ++mt) {
        #pragma unroll
        for (int nt = 0; nt < 8; ++nt) {
            const int n_g = n0 + nt * 16 + (lane & 15);
            const float bv = Bias_s[nt * 16 + (lane & 15)];
            #pragma unroll
            for (int r = 0; r < 4; ++r) {
                const int m_g = m0 + wv * 32 + mt * 16 + (lane >> 4) * 4 + r;
                const int b = m_g >> 11, t = m_g & 2047;
                const size_t off = (((size_t)(b >> 4) * T_ + t) * G_ + n_g) * 16 + (b & 15);
                xg[off] = __float2bfloat16(acc[mt][nt][r] + bv);
            }
        }
    }
}

// ---------------------------------------------------------------------------
// Layer 1 MFMA scan. Same structure; xg pre-laid-out, loaded into registers
// (double-buffered per 4-step window). Writes h history to l1h.
// ---------------------------------------------------------------------------
__global__ __launch_bounds__(512, 2) void gru_l1_mfma(
    const bf16* __restrict__ xg_f, const bf16* __restrict__ xg_r,
    const float* __restrict__ whh_f, const float* __restrict__ bhh_f,
    const float* __restrict__ whh_r, const float* __restrict__ bhh_r,
    bf16* __restrict__ l1h, int fixed_dir)
{
    const int bx   = blockIdx.x;
    const int dir  = (fixed_dir >= 0) ? fixed_dir : (bx >> 2);
    const int bg   = bx & 3;
    const int b0   = bg * 16;
    const int tid  = threadIdx.x;
    const int lane = tid & 63;
    const int wv   = tid >> 6;
    const int col  = lane & 15;
    const int quad = lane >> 4;
    const int jcol = wv * 16 + col;

    const bf16*  XG  = dir ? xg_r : xg_f;
    const float* Whh = dir ? whh_r : whh_f;
    const float* Bhh = dir ? bhh_r : bhh_f;

    __shared__ __align__(16) bf16 hring[RING][16 * HSTR];

    s16x8 bfr[3][4];
    #pragma unroll
    for (int g = 0; g < 3; ++g) {
        const float* wrow = Whh + (size_t)(g * H_ + jcol) * H_;
        #pragma unroll
        for (int kt = 0; kt < 4; ++kt) {
            const float* p = wrow + kt * 32 + quad * 8;
            s16x8 f;
            #pragma unroll
            for (int i = 0; i < 8; ++i) f[i] = f2bs(p[i]);
            bfr[g][kt] = f;
        }
    }
    const float cr  = Bhh[jcol];
    const float cz  = Bhh[H_ + jcol];
    const float cnh = Bhh[2*H_ + jcol];

    for (int i = tid; i < 16 * HSTR; i += 512) hring[0][i] = __float2bfloat16(0.0f);

    float hprev[4] = {0.f, 0.f, 0.f, 0.f};
    const bf16* xgb = XG + (size_t)bg * T_ * G_ * 16;

    uint2 xgA[WIN][3], xgB[WIN][3];
    #pragma unroll
    for (int si = 0; si < WIN; ++si) {
        const int t = dir ? (T_ - 1 - si) : si;
        #pragma unroll
        for (int g = 0; g < 3; ++g)
            xgA[si][g] = *(const uint2*)(xgb + (((size_t)t * G_) + g * H_ + jcol) * 16 + quad * 4);
    }
    __syncthreads();

    auto run_window = [&](int w, uint2 (&xcur)[WIN][3], uint2 (&xnxt)[WIN][3]) {
        #pragma unroll
        for (int si = 0; si < WIN; ++si) {
            const int s  = w * WIN + si;
            if (si == 0 && w + 1 < NW) {
                #pragma unroll
                for (int sj = 0; sj < WIN; ++sj) {
                    const int s2 = (w + 1) * WIN + sj;
                    const int t2 = dir ? (T_ - 1 - s2) : s2;
                    #pragma unroll
                    for (int g = 0; g < 3; ++g)
                        xnxt[sj][g] = *(const uint2*)(xgb + (((size_t)t2 * G_) + g * H_ + jcol) * 16 + quad * 4);
                }
            }
            const int rb = s % RING;
            const int wb = (s + 1) % RING;

            s16x8 afr[4];
            #pragma unroll
            for (int kt = 0; kt < 4; ++kt)
                afr[kt] = *(const s16x8*)&hring[rb][col * HSTR + kt * 32 + quad * 8];

            f32x4 aR = (f32x4){0.f,0.f,0.f,0.f};
            f32x4 aZ = aR, aN = aR;
            #pragma unroll
            for (int kt = 0; kt < 4; ++kt) {
                aR = __builtin_amdgcn_mfma_f32_16x16x32_bf16(afr[kt], bfr[0][kt], aR, 0, 0, 0);
                aZ = __builtin_amdgcn_mfma_f32_16x16x32_bf16(afr[kt], bfr[1][kt], aZ, 0, 0, 0);
                aN = __builtin_amdgcn_mfma_f32_16x16x32_bf16(afr[kt], bfr[2][kt], aN, 0, 0, 0);
            }
            const uint2 xr2 = xcur[si][0], xz2 = xcur[si][1], xn2 = xcur[si][2];
            const unsigned short xru[4] = {(unsigned short)(xr2.x & 0xffffu), (unsigned short)(xr2.x >> 16),
                                           (unsigned short)(xr2.y & 0xffffu), (unsigned short)(xr2.y >> 16)};
            const unsigned short xzu[4] = {(unsigned short)(xz2.x & 0xffffu), (unsigned short)(xz2.x >> 16),
                                           (unsigned short)(xz2.y & 0xffffu), (unsigned short)(xz2.y >> 16)};
            const unsigned short xnu[4] = {(unsigned short)(xn2.x & 0xffffu), (unsigned short)(xn2.x >> 16),
                                           (unsigned short)(xn2.y & 0xffffu), (unsigned short)(xn2.y >> 16)};
            #pragma unroll
            for (int r = 0; r < 4; ++r) {
                const float rg = sigf(us2f(xru[r]) + aR[r] + cr);
                const float zg = sigf(us2f(xzu[r]) + aZ[r] + cz);
                const float ng = tanhf_(us2f(xnu[r]) + rg * (aN[r] + cnh));
                const float hn = ng + zg * (hprev[r] - ng);
                hprev[r] = hn;
                hring[wb][(quad * 4 + r) * HSTR + jcol] = __float2bfloat16(hn);
            }
            __syncthreads();
        }
        #pragma unroll
        for (int k = 0; k < 2; ++k) {
            const int c  = tid + k * 512;
            const int dt = c >> 8, m = (c >> 4) & 15, j8 = c & 15;
            const int s  = w * WIN + dt;
            const int t  = dir ? (T_ - 1 - s) : s;
            const uint4 v = *(const uint4*)&hring[(s + 1) % RING][m * HSTR + j8 * 8];
            *(uint4*)(l1h + ((size_t)(b0 + m) * T_ + t) * 256 + dir * H_ + j8 * 8) = v;
        }
        __syncthreads();
    };

    for (int w = 0; w < NW; w += 2) {
        run_window(w,     xgA, xgB);
        run_window(w + 1, xgB, xgA);
    }
}

// ---------------------------------------------------------------------------
// FC epilogue: out[bt][c] = fc_b[c] + fc_w[c][:] . l1h[bt][:]
// ---------------------------------------------------------------------------
__global__ __launch_bounds__(256, 2) void fc_kernel(
    const bf16* __restrict__ h, const float* __restrict__ fcw,
    const float* __restrict__ fcb, float* __restrict__ out)
{
    __shared__ float w0[256], w1[256];
    const int tid = threadIdx.x;
    w0[tid] = fcw[tid];
    w1[tid] = fcw[256 + tid];
    __syncthreads();

    const size_t bt = (size_t)blockIdx.x * 256 + tid;
    const bf16* hp = h + bt * 256;
    float s0 = fcb[0], s1 = fcb[1];
    #pragma unroll 4
    for (int k8 = 0; k8 < 32; ++k8) {
        const uint4 u = *(const uint4*)(hp + k8 * 8);
        const unsigned uu[4] = {u.x, u.y, u.z, u.w};
        #pragma unroll
        for (int p = 0; p < 4; ++p) {
            const float v0 = __uint_as_float(uu[p] << 16);
            const float v1 = __uint_as_float(uu[p] & 0xffff0000u);
            const int k = k8 * 8 + p * 2;
            s0 = fmaf(w0[k], v0, s0);     s1 = fmaf(w1[k], v0, s1);
            s0 = fmaf(w0[k + 1], v1, s0); s1 = fmaf(w1[k + 1], v1, s1);
        }
    }
    out[bt * 2]     = s0;
    out[bt * 2 + 1] = s1;
}

extern "C" void kernel_launch(void* const* d_in, const int* in_sizes, int n_in,
                              void* d_out, int out_size, void* d_ws, size_t ws_size,
                              hipStream_t stream)
{
    if (n_in < 19) return;
    const float* x     = (const float*)d_in[0];
    const float* wih0  = (const float*)d_in[1];
    const float* whh0  = (const float*)d_in[2];
    const float* bih0  = (const float*)d_in[3];
    const float* bhh0  = (const float*)d_in[4];
    const float* wih0r = (const float*)d_in[5];
    const float* whh0r = (const float*)d_in[6];
    const float* bih0r = (const float*)d_in[7];
    const float* bhh0r = (const float*)d_in[8];
    const float* wih1  = (const float*)d_in[9];
    const float* whh1  = (const float*)d_in[10];
    const float* bih1  = (const float*)d_in[11];
    const float* bhh1  = (const float*)d_in[12];
    const float* wih1r = (const float*)d_in[13];
    const float* whh1r = (const float*)d_in[14];
    const float* bih1r = (const float*)d_in[15];
    const float* bhh1r = (const float*)d_in[16];
    const float* fcw   = (const float*)d_in[17];
    const float* fcb   = (const float*)d_in[18];
    float* out = (float*)d_out;

    const size_t nBT  = (size_t)B_ * T_;
    const size_t hh_b = nBT * 2 * H_ * sizeof(bf16);     // 64 MiB
    const size_t xg_b = nBT * G_ * sizeof(bf16);         // 96 MiB per dir
    const size_t xg_el = nBT * G_;

    bf16* l0h = (bf16*)d_ws;
    bf16* xgf = (bf16*)((char*)d_ws + hh_b);
    bf16* xgr = xgf + xg_el;

    if (ws_size >= hh_b + 2 * xg_b) {
        // l1h aliases l0h (dead after the GEMMs)
        gru_l0_mfma<<<dim3(8), dim3(512), 0, stream>>>(
            x, wih0, whh0, bih0, bhh0, wih0r, whh0r, bih0r, bhh0r, l0h);
        xg_gemm_mfma<<<dim3(1024, 3), dim3(256), 0, stream>>>(l0h, wih1,  bih1,  xgf);
        xg_gemm_mfma<<<dim3(1024, 3), dim3(256), 0, stream>>>(l0h, wih1r, bih1r, xgr);
        gru_l1_mfma<<<dim3(8), dim3(512), 0, stream>>>(
            xgf, xgr, whh1, bhh1, whh1r, bhh1r, l0h, -1);
        fc_kernel<<<dim3((int)(nBT / 256)), dim3(256), 0, stream>>>(l0h, fcw, fcb, out);
    } else if (ws_size >= 2 * hh_b + xg_b) {
        // sequential dirs, separate l1h so l0h survives both GEMMs
        bf16* l1h = (bf16*)((char*)d_ws + hh_b + xg_b);
        gru_l0_mfma<<<dim3(8), dim3(512), 0, stream>>>(
            x, wih0, whh0, bih0, bhh0, wih0r, whh0r, bih0r, bhh0r, l0h);
        xg_gemm_mfma<<<dim3(1024, 3), dim3(256), 0, stream>>>(l0h, wih1, bih1, xgf);
        gru_l1_mfma<<<dim3(4), dim3(512), 0, stream>>>(
            xgf, xgf, whh1, bhh1, whh1r, bhh1r, l1h, 0);
        xg_gemm_mfma<<<dim3(1024, 3), dim3(256), 0, stream>>>(l0h, wih1r, bih1r, xgf);
        gru_l1_mfma<<<dim3(4), dim3(512), 0, stream>>>(
            xgf, xgf, whh1, bhh1, whh1r, bhh1r, l1h, 1);
        fc_kernel<<<dim3((int)(nBT / 256)), dim3(256), 0, stream>>>(l1h, fcw, fcb, out);
    }
}